// Round 1
// baseline (165.959 us; speedup 1.0000x reference)
//
#include <hip/hip_runtime.h>

#define NB 4
#define NN 2048
#define NF 256
#define NK 4
#define ND 64
#define NEG 0.2f

typedef _Float16 f16;
typedef _Float16 f16x4 __attribute__((ext_vector_type(4)));
typedef float f32x4 __attribute__((ext_vector_type(4)));

// ---------------------------------------------------------------------------
// K1: Wh^T = (x @ W)^T per (b,k), stored f16 as wht[b][k][d][n]; also
// s[b,k,n] = Wh·a_src, t[b,k,n] = Wh·a_dst in f32 (from the f32 accumulators).
// Computed as out'[d'][n] = sum_f W^T[d'][f] * x[n][f]:
//   A = W^T (64 x 256) staged in LDS (xor-swizzled), B = x rows read directly
//   from global (8 consecutive f = contiguous), C rows = d', cols = n.
// Block: 256 thr = 4 waves; tile 64 d' x 128 n; wave owns 32 n-cols.
// ---------------------------------------------------------------------------
__global__ __launch_bounds__(256) void k1_gemm(
    const float* __restrict__ x,      // (B,N,F)
    const float* __restrict__ Wm,     // (K,F,D)
    const float* __restrict__ a_src,  // (K,D)
    const float* __restrict__ a_dst,  // (K,D)
    f16* __restrict__ wht,            // (B,K,D,N)
    float* __restrict__ sbuf,         // (B,K,N)
    float* __restrict__ tbuf)         // (B,K,N)
{
    const int gx  = blockIdx.x;   // n-group of 128
    const int k   = blockIdx.y;
    const int b   = blockIdx.z;
    const int tid = threadIdx.x;
    const int wv  = tid >> 6;
    const int l   = tid & 63;
    const int q   = l >> 4;
    const int r16 = l & 15;

    __shared__ f16 wt[64 * 256];  // W^T: wt[d][f], xor-swizzled in f

    // stage W^T (coalesced global read, swizzled LDS write; once per block)
    for (int fc = 0; fc < 64; ++fc) {
        int f = fc * 4 + wv;
        int d = l;
        wt[d * 256 + (f ^ ((d & 7) << 3))] = (f16)Wm[(k * NF + f) * ND + d];
    }
    __syncthreads();

    const int ncol0 = gx * 128 + wv * 32;
    f32x4 acc[2][4];
#pragma unroll
    for (int nt = 0; nt < 2; ++nt)
#pragma unroll
        for (int dt = 0; dt < 4; ++dt)
            acc[nt][dt] = (f32x4){0.f, 0.f, 0.f, 0.f};

    for (int fs = 0; fs < 16; ++fs) {           // K-steps of 16
        const int f0 = fs * 16 + q * 4;          // this lane's 4 k-elems
        f16x4 af[4];
#pragma unroll
        for (int dt = 0; dt < 4; ++dt) {
            int d = dt * 16 + r16;               // A row
            af[dt] = *(const f16x4*)&wt[d * 256 + (f0 ^ ((d & 7) << 3))];
        }
#pragma unroll
        for (int nt = 0; nt < 2; ++nt) {
            int n = ncol0 + nt * 16 + r16;       // B col
            float4 xv = *(const float4*)&x[((size_t)(b * NN + n)) * NF + f0];
            f16x4 bf = {(f16)xv.x, (f16)xv.y, (f16)xv.z, (f16)xv.w};
#pragma unroll
            for (int dt = 0; dt < 4; ++dt)
                acc[nt][dt] = __builtin_amdgcn_mfma_f32_16x16x16f16(
                    af[dt], bf, acc[nt][dt], 0, 0, 0);
        }
    }

    // a_src/a_dst values for this lane's C rows
    float asv[4][4], adv[4][4];
#pragma unroll
    for (int dt = 0; dt < 4; ++dt)
#pragma unroll
        for (int rr = 0; rr < 4; ++rr) {
            int d = dt * 16 + q * 4 + rr;
            asv[dt][rr] = a_src[k * ND + d];
            adv[dt][rr] = a_dst[k * ND + d];
        }

#pragma unroll
    for (int nt = 0; nt < 2; ++nt) {
        int n = ncol0 + nt * 16 + r16;
        float sp = 0.f, tp = 0.f;
#pragma unroll
        for (int dt = 0; dt < 4; ++dt)
#pragma unroll
            for (int rr = 0; rr < 4; ++rr) {
                float v = acc[nt][dt][rr];
                int d = dt * 16 + q * 4 + rr;    // C row = d'
                wht[((size_t)(b * NK + k) * ND + d) * NN + n] = (f16)v;
                sp += v * asv[dt][rr];
                tp += v * adv[dt][rr];
            }
        // reduce across the four quarter-groups (each covers distinct d's)
        sp += __shfl_xor(sp, 16);
        sp += __shfl_xor(sp, 32);
        tp += __shfl_xor(tp, 16);
        tp += __shfl_xor(tp, 32);
        if (q == 0) {
            sbuf[(b * NK + k) * NN + n] = sp;
            tbuf[(b * NK + k) * NN + n] = tp;
        }
    }
}

// ---------------------------------------------------------------------------
// K2: fused masked-softmax attention.
// Scores are rank-1: e[i,j] = lrelu(s_i + t_j); shift-invariant softmax with
// shift_i = lrelu(s_i) bounds w = exp(lrelu(s+t)-shift) <= ~e^8 (f16-safe).
// Block: 16 i-rows x one b; 4 waves = 4 heads. Per 32-j tile each lane
// computes exactly its A-fragment's 8 P elements (i = l&15, j = 4q+e / +16),
// B-fragments read straight from wht (contiguous j). No LDS.
// ---------------------------------------------------------------------------
__global__ __launch_bounds__(256) void k2_attn(
    const int* __restrict__ adj,     // (B,N,N)
    const f16* __restrict__ wht,     // (B,K,D,N)
    const float* __restrict__ sbuf,  // (B,K,N)
    const float* __restrict__ tbuf,  // (B,K,N)
    float* __restrict__ out)         // (B,N,K*D)
{
    const int i0  = blockIdx.x * 16;
    const int b   = blockIdx.y;
    const int tid = threadIdx.x;
    const int k   = tid >> 6;
    const int l   = tid & 63;
    const int q   = l >> 4;
    const int r16 = l & 15;
    const int iglob = i0 + r16;

    const float s_lane = sbuf[(b * NK + k) * NN + iglob];
    const float shift  = fmaxf(s_lane, 0.f) + NEG * fminf(s_lane, 0.f);
    const float* __restrict__ trow = tbuf + (b * NK + k) * NN;
    const int*   __restrict__ arow = adj + ((size_t)(b * NN) + iglob) * NN;
    const f16*   __restrict__ whb  = wht + (size_t)(b * NK + k) * ND * NN;

    float denom = 0.f;
    f32x4 acc[4];
#pragma unroll
    for (int dt = 0; dt < 4; ++dt) acc[dt] = (f32x4){0.f, 0.f, 0.f, 0.f};

    for (int j0 = 0; j0 < NN; j0 += 32) {
        const int ja = j0 + q * 4;       // first K=16 half: k-dim 4q+e
        const int jb = ja + 16;          // second half
        float4 t0 = *(const float4*)(trow + ja);
        float4 t1 = *(const float4*)(trow + jb);
        int4  a0  = *(const int4*)(arow + ja);
        int4  a1  = *(const int4*)(arow + jb);
        float tv0[4] = {t0.x, t0.y, t0.z, t0.w};
        float tv1[4] = {t1.x, t1.y, t1.z, t1.w};
        int   av0[4] = {a0.x, a0.y, a0.z, a0.w};
        int   av1[4] = {a1.x, a1.y, a1.z, a1.w};
        float w0[4], w1[4];
#pragma unroll
        for (int e = 0; e < 4; ++e) {
            float e0  = s_lane + tv0[e];
            float le0 = fmaxf(e0, 0.f) + NEG * fminf(e0, 0.f);
            w0[e] = ((av0[e] > 0) || (ja + e == iglob)) ? __expf(le0 - shift) : 0.f;
            float e1  = s_lane + tv1[e];
            float le1 = fmaxf(e1, 0.f) + NEG * fminf(e1, 0.f);
            w1[e] = ((av1[e] > 0) || (jb + e == iglob)) ? __expf(le1 - shift) : 0.f;
            denom += w0[e] + w1[e];
        }
        f16x4 pa0 = {(f16)w0[0], (f16)w0[1], (f16)w0[2], (f16)w0[3]};
        f16x4 pa1 = {(f16)w1[0], (f16)w1[1], (f16)w1[2], (f16)w1[3]};
#pragma unroll
        for (int dt = 0; dt < 4; ++dt) {
            const f16* wrow = whb + (size_t)(dt * 16 + r16) * NN;
            f16x4 bf0 = *(const f16x4*)(wrow + ja);
            f16x4 bf1 = *(const f16x4*)(wrow + jb);
            acc[dt] = __builtin_amdgcn_mfma_f32_16x16x16f16(pa0, bf0, acc[dt], 0, 0, 0);
            acc[dt] = __builtin_amdgcn_mfma_f32_16x16x16f16(pa1, bf1, acc[dt], 0, 0, 0);
        }
    }

    // row denominators: reduce across quarter-groups (all lanes get their row's sum)
    denom += __shfl_xor(denom, 16);
    denom += __shfl_xor(denom, 32);

#pragma unroll
    for (int rr = 0; rr < 4; ++rr) {
        int irow = q * 4 + rr;                       // C row
        float dd  = __shfl(denom, (l & 48) | irow);  // lane holding that row
        float inv = 1.f / (dd + 1e-10f);
#pragma unroll
        for (int dt = 0; dt < 4; ++dt)
            out[((size_t)(b * NN) + i0 + irow) * (NK * ND) + k * ND + dt * 16 + r16] =
                acc[dt][rr] * inv;
    }
}

extern "C" void kernel_launch(void* const* d_in, const int* in_sizes, int n_in,
                              void* d_out, int out_size, void* d_ws, size_t ws_size,
                              hipStream_t stream) {
    const float* x     = (const float*)d_in[0];
    const int*   adj   = (const int*)d_in[1];
    const float* Wm    = (const float*)d_in[2];
    const float* a_src = (const float*)d_in[3];
    const float* a_dst = (const float*)d_in[4];
    float* out = (float*)d_out;

    char* ws = (char*)d_ws;
    f16*   wht  = (f16*)ws;                                   // 4 MiB
    float* sbuf = (float*)(ws + (4u << 20));                  // 128 KiB
    float* tbuf = (float*)(ws + (4u << 20) + NB * NK * NN * sizeof(float));

    k1_gemm<<<dim3(16, NK, NB), 256, 0, stream>>>(x, Wm, a_src, a_dst, wht, sbuf, tbuf);
    k2_attn<<<dim3(NN / 16, NB), 256, 0, stream>>>(adj, wht, sbuf, tbuf, out);
}